// Round 1
// baseline (625.949 us; speedup 1.0000x reference)
//
#include <hip/hip_runtime.h>

// Problem constants (fixed by setup_inputs)
#define NROWS 800000
#define SEGROWS 100000
// ws float layout:
//   [0..4095]      M2 (X^T X, 64x64)           written by k2a
//   [4096..4607]   segment sums (8x64)          written by k2a
//   [4608..8703]   W' = W1a * s[c] (64x64)      written by k2b
//   [8704..9215]   tb (8x64)                    written by k2b
//   [9216.. )      per-block partials, stride 4160 (4096 M2 + 64 sums)

// ---------------- K1: segment sums + per-block M2 partials ----------------
__global__ __launch_bounds__(256, 2)
void k1_stats(const float* __restrict__ x, float* __restrict__ part, int rowsPerBlk)
{
    __shared__ __align__(16) float tile[64 * 68]; // 17408 B; reused as reduce buffer
    float4* T4 = (float4*)tile;
    const float4* X4 = (const float4*)x;
    int t = threadIdx.x, w = t >> 6, l = t & 63, tj = l >> 3, tk = l & 7;
    size_t r0 = (size_t)blockIdx.x * rowsPerBlk;

    float acc[64];
#pragma unroll
    for (int i = 0; i < 64; ++i) acc[i] = 0.f;
    float s0 = 0, s1 = 0, s2 = 0, s3 = 0;

    for (int base = 0; base < rowsPerBlk; base += 64) {
        int nr = min(64, rowsPerBlk - base);
        __syncthreads(); // protect previous tile reads
        int nf = nr * 16;
        for (int f = t; f < nf; f += 256) {
            int row = f >> 4, c4 = f & 15; // thread's channels fixed: c4 = t&15
            float4 v = X4[(r0 + base + row) * 16 + c4];
            T4[row * 17 + c4] = v;
            s0 += v.x; s1 += v.y; s2 += v.z; s3 += v.w;
        }
        __syncthreads();
        for (int r = w; r < nr; r += 4) { // wave-interleaved rows, lanes = 8x8 (tj,tk)
            float4 a0 = T4[r * 17 + 2 * tj], a1 = T4[r * 17 + 2 * tj + 1];
            float4 b0 = T4[r * 17 + 2 * tk], b1 = T4[r * 17 + 2 * tk + 1];
            float aj[8] = {a0.x, a0.y, a0.z, a0.w, a1.x, a1.y, a1.z, a1.w};
            float bk[8] = {b0.x, b0.y, b0.z, b0.w, b1.x, b1.y, b1.z, b1.w};
#pragma unroll
            for (int p = 0; p < 8; ++p)
#pragma unroll
                for (int q = 0; q < 8; ++q)
                    acc[p * 8 + q] = fmaf(aj[p], bk[q], acc[p * 8 + q]);
        }
    }
    // ---- segment-sum reduce (channel of thread t, comp i = 4*(t&15)+i) ----
    __syncthreads();
    T4[t] = make_float4(s0, s1, s2, s3);
    __syncthreads();
    if (t < 64) {
        float s = 0;
#pragma unroll
        for (int u = 0; u < 16; ++u) s += tile[4 * ((t >> 2) + 16 * u) + (t & 3)];
        part[(size_t)blockIdx.x * 4160 + 4096 + t] = s;
    }
    __syncthreads();
    // ---- M2 reduce across 4 waves into tile[0..4095] ----
    if (w == 0) {
#pragma unroll
        for (int p = 0; p < 8; ++p)
#pragma unroll
            for (int q = 0; q < 8; ++q)
                tile[(8 * tj + p) * 64 + 8 * tk + q] = acc[p * 8 + q];
    }
    __syncthreads();
    for (int ww = 1; ww < 4; ++ww) {
        if (w == ww) {
#pragma unroll
            for (int p = 0; p < 8; ++p)
#pragma unroll
                for (int q = 0; q < 8; ++q)
                    tile[(8 * tj + p) * 64 + 8 * tk + q] += acc[p * 8 + q];
        }
        __syncthreads();
    }
    float4* P4 = (float4*)(part + (size_t)blockIdx.x * 4160);
    for (int f = t; f < 1024; f += 256) P4[f] = T4[f];
}

// ---------------- K2a: reduce partials -> M2, segment sums ----------------
__global__ __launch_bounds__(256)
void k2a_reduce(const float* __restrict__ part, float* __restrict__ m2,
                float* __restrict__ ssum, int P)
{
    int t = threadIdx.x, b = blockIdx.x;
    if (b < 16) {
        int e = b * 256 + t;
        float s = 0;
#pragma unroll 4
        for (int i = 0; i < P; ++i) s += part[(size_t)i * 4160 + e];
        m2[e] = s;
    } else {
        int idx = (b - 16) * 256 + t; // 0..511 -> (seg, channel)
        int sg = idx >> 6, c = idx & 63, bp = P >> 3;
        float s = 0;
#pragma unroll 4
        for (int i = 0; i < bp; ++i) s += part[(size_t)(sg * bp + i) * 4160 + 4096 + c];
        ssum[idx] = s;
    }
}

// ---------------- K2b: tiny algebra -> W', tb ----------------
__global__ __launch_bounds__(256)
void k2b_solve(const int* __restrict__ o,
               const float* __restrict__ w2, const float* __restrict__ b2,
               const float* __restrict__ w1, const float* __restrict__ b1,
               const float* __restrict__ gamma, const float* __restrict__ beta,
               const float* __restrict__ m2, const float* __restrict__ ssum,
               float* __restrict__ wp, float* __restrict__ tbout)
{
    __shared__ float means[512], hb[512], cv[512], Sx[64], cnts[8], muS[64], sS[64], q1p[256];
    int t = threadIdx.x;
    if (t < 8) cnts[t] = (float)(o[t] - (t ? o[t - 1] : 0));
    __syncthreads();
    for (int i = t; i < 512; i += 256) means[i] = ssum[i] / cnts[i >> 6];
    __syncthreads();
    int c = t & 63, g = t >> 6;
    for (int b = g; b < 8; b += 4) { // h = relu(means @ w2.T + b2)
        float a = b2[c];
        for (int k = 0; k < 64; ++k) a = fmaf(means[b * 64 + k], w2[c * 64 + k], a);
        hb[b * 64 + c] = fmaxf(a, 0.f);
    }
    __syncthreads();
    for (int b = g; b < 8; b += 4) { // cvec = W1b @ h + b1
        float a = b1[c];
        for (int k = 0; k < 64; ++k) a = fmaf(hb[b * 64 + k], w1[c * 128 + 64 + k], a);
        cv[b * 64 + c] = a;
    }
    __syncthreads();
    if (t < 64) {
        float s = 0;
        for (int b = 0; b < 8; ++b) s += ssum[b * 64 + t];
        Sx[t] = s;
    }
    __syncthreads();
    { // q1 partials: w_c^T M2 w_c split over j-ranges
        float p = 0;
        for (int j = g * 16; j < g * 16 + 16; ++j) {
            float vj = 0;
            for (int k = 0; k < 64; ++k) vj = fmaf(w1[c * 128 + k], m2[j * 64 + k], vj);
            p = fmaf(w1[c * 128 + j], vj, p);
        }
        q1p[g * 64 + c] = p;
    }
    __syncthreads();
    if (t < 64) {
        const float Nf = (float)NROWS;
        float mu = 0;
        for (int k = 0; k < 64; ++k) mu = fmaf(w1[t * 128 + k], Sx[k], mu);
        float q2 = 0, q3 = 0, msum = 0;
        for (int b = 0; b < 8; ++b) {
            float gv = cv[b * 64 + t];
            msum += cnts[b] * gv;
            q3 = fmaf(cnts[b] * gv, gv, q3);
            float dot = 0;
            for (int k = 0; k < 64; ++k) dot = fmaf(w1[t * 128 + k], ssum[b * 64 + k], dot);
            q2 = fmaf(2.f * gv, dot, q2);
        }
        mu = (mu + msum) / Nf;
        float q1 = q1p[t] + q1p[64 + t] + q1p[128 + t] + q1p[192 + t];
        float var = (q1 + q2 + q3) / Nf - mu * mu;
        float s = gamma[t] * rsqrtf(var + 1e-5f);
        muS[t] = mu; sS[t] = s;
    }
    __syncthreads();
    for (int f = t; f < 4096; f += 256) wp[f] = w1[(f >> 6) * 128 + (f & 63)] * sS[f >> 6];
    for (int f = t; f < 512; f += 256)
        tbout[f] = (cv[f] - muS[f & 63]) * sS[f & 63] + beta[f & 63];
}

// ---------------- K3: out = relu(x @ W'^T + tb[seg]) ----------------
__global__ __launch_bounds__(256, 2)
void k3_gemm(const float* __restrict__ x, const float* __restrict__ wp,
             const float* __restrict__ tb, float* __restrict__ out)
{
    __shared__ __align__(16) float tile[256 * 68]; // 69632 B, pad 68 breaks bank aliasing
    __shared__ float tbs[512];
    float4* T4 = (float4*)tile;
    const float4* X4 = (const float4*)x;
    float4* O4 = (float4*)out;
    int t = threadIdx.x;
    size_t r0 = (size_t)blockIdx.x * 256;

    for (int i = t; i < 512; i += 256) tbs[i] = tb[i];
#pragma unroll 4
    for (int p = 0; p < 16; ++p) { // coalesced global -> LDS (16 lanes per 256B row)
        int f = t + 256 * p, row = f >> 4, c4 = f & 15;
        T4[row * 17 + c4] = X4[(r0 + row) * 16 + c4];
    }
    __syncthreads();

    int row = t;
    int seg = ((int)r0 + row) / SEGROWS;
    float xr[64]; // whole row register-resident
#pragma unroll
    for (int j = 0; j < 16; ++j) {
        float4 v = T4[row * 17 + j];
        xr[4 * j] = v.x; xr[4 * j + 1] = v.y; xr[4 * j + 2] = v.z; xr[4 * j + 3] = v.w;
    }
    const float* tbr = &tbs[seg * 64];
    for (int cq = 0; cq < 16; ++cq) { // W' indices wave-uniform -> s_load + v_fmac(s,v)
        float4 res;
#pragma unroll
        for (int ci = 0; ci < 4; ++ci) {
            int c = cq * 4 + ci;
            const float* wr = wp + c * 64;
            float a0 = 0, a1 = 0, a2 = 0, a3 = 0;
#pragma unroll
            for (int k = 0; k < 64; k += 4) {
                a0 = fmaf(wr[k], xr[k], a0);
                a1 = fmaf(wr[k + 1], xr[k + 1], a1);
                a2 = fmaf(wr[k + 2], xr[k + 2], a2);
                a3 = fmaf(wr[k + 3], xr[k + 3], a3);
            }
            float v = (a0 + a1) + (a2 + a3) + tbr[c];
            ((float*)&res)[ci] = fmaxf(v, 0.f);
        }
        T4[row * 17 + cq] = res; // own row only: no cross-thread hazard
    }
    __syncthreads();
#pragma unroll 4
    for (int p = 0; p < 16; ++p) { // coalesced LDS -> global
        int f = t + 256 * p, row2 = f >> 4, c4 = f & 15;
        O4[(r0 + row2) * 16 + c4] = T4[row2 * 17 + c4];
    }
}

extern "C" void kernel_launch(void* const* d_in, const int* in_sizes, int n_in,
                              void* d_out, int out_size, void* d_ws, size_t ws_size,
                              hipStream_t stream)
{
    const float* x  = (const float*)d_in[0];
    const int*   o  = (const int*)d_in[1];
    const float* w2 = (const float*)d_in[2];
    const float* b2 = (const float*)d_in[3];
    const float* w1 = (const float*)d_in[4];
    const float* b1 = (const float*)d_in[5];
    const float* gm = (const float*)d_in[6];
    const float* bt = (const float*)d_in[7];
    float* out = (float*)d_out;
    float* ws  = (float*)d_ws;

    float* m2   = ws;
    float* ssum = ws + 4096;
    float* wp   = ws + 4608;
    float* tb   = ws + 8704;
    float* part = ws + 9216;

    // pick partial count that fits ws (all choices keep blocks inside one segment)
    int P = 800;
    if (ws_size < (size_t)(9216 + (size_t)800 * 4160) * 4) P = 256;
    if (ws_size < (size_t)(9216 + (size_t)256 * 4160) * 4) P = 64;
    int rpb = NROWS / P;

    k1_stats<<<P, 256, 0, stream>>>(x, part, rpb);
    k2a_reduce<<<18, 256, 0, stream>>>(part, m2, ssum, P);
    k2b_solve<<<1, 256, 0, stream>>>(o, w2, b2, w1, b1, gm, bt, m2, ssum, wp, tb);
    k3_gemm<<<3125, 256, 0, stream>>>(x, wp, tb, out);
}

// Round 2
// 474.532 us; speedup vs baseline: 1.3191x; 1.3191x over previous
//
#include <hip/hip_runtime.h>

#define NROWS 800000
#define SEGROWS 100000
#define K1_BLOCKS 800
#define K1_ROWS 1000
// ws float layout:
//   [0..4096)     M2 (atomic-accumulated by k1)
//   [4096..4608)  segment sums (atomic-accumulated by k1)
//   [4608..5120)  tb fp32 (written by k2b)
//   [5120..7168)  wpb: W' as bf16 ushort[64*64], row-major [c][k] (written by k2b)

typedef __attribute__((ext_vector_type(8))) short bf16x8;
typedef __attribute__((ext_vector_type(4))) float f32x4;
typedef __attribute__((ext_vector_type(4))) short short4v;

__device__ inline unsigned short f2bf(float f) { // RNE fp32 -> bf16
    unsigned u = __builtin_bit_cast(unsigned, f);
    return (unsigned short)((u + 0x7FFFu + ((u >> 16) & 1u)) >> 16);
}

// ---------------- K0: zero the atomic accumulators ----------------
__global__ void kzero(float* __restrict__ p) {
    int t = blockIdx.x * 256 + threadIdx.x;
    if (t < 4608) p[t] = 0.f;
}

// ---------------- K1: M2 = X^T X (bf16 MFMA) + segment sums ----------------
// A-frag == B-frag trick: frag(l,j) = x[r0+8*(l>>4)+j][c0+(l&15)] serves both operands.
__global__ __launch_bounds__(256, 2)
void k1_stats(const float* __restrict__ x, float* __restrict__ m2g, float* __restrict__ ssumg)
{
    __shared__ __align__(16) float smem[5120];   // 20 KB: xt (17408 B) then reduce bufs
    short* xt = (short*)smem;                    // xt[col][row], stride 136 shorts (128+8 pad)
    const float4* X4 = (const float4*)x;
    int t = threadIdx.x, w = t >> 6, lane = t & 63;
    int c4 = t & 15, g = t >> 4;
    size_t r0 = (size_t)blockIdx.x * K1_ROWS;
    int seg = (int)(r0 / SEGROWS);               // blocks are segment-aligned (1000 | 100000)

    f32x4 acc[4][4];
#pragma unroll
    for (int p = 0; p < 4; ++p)
#pragma unroll
        for (int q = 0; q < 4; ++q) acc[p][q] = (f32x4){0.f, 0.f, 0.f, 0.f};
    float s0 = 0, s1 = 0, s2 = 0, s3 = 0;

    for (int tile = 0; tile < K1_ROWS; tile += 128) {
        int nr = min(128, K1_ROWS - tile);       // 128 or 104 (104 % 8 == 0: clean pieces)
        __syncthreads();                         // previous tile's frag reads done
#pragma unroll
        for (int h = 0; h < 2; ++h) {            // piece: 4 rows x 4 cols, transposed store
            int rg = 8 * g + 4 * h;
            float4 v[4];
#pragma unroll
            for (int i = 0; i < 4; ++i) {
                int r = rg + i;
                if (r < nr) {
                    v[i] = X4[(r0 + tile + r) * 16 + c4];
                    s0 += v[i].x; s1 += v[i].y; s2 += v[i].z; s3 += v[i].w;
                } else v[i] = make_float4(0.f, 0.f, 0.f, 0.f);
            }
#pragma unroll
            for (int j = 0; j < 4; ++j) {        // col 4*c4+j gets rows rg..rg+3
                short4v pk;
                pk[0] = (short)f2bf(((const float*)&v[0])[j]);
                pk[1] = (short)f2bf(((const float*)&v[1])[j]);
                pk[2] = (short)f2bf(((const float*)&v[2])[j]);
                pk[3] = (short)f2bf(((const float*)&v[3])[j]);
                *(short4v*)&xt[(4 * c4 + j) * 136 + rg] = pk;
            }
        }
        __syncthreads();
        // wave w owns k-chunk rows 32w..32w+31; one frag per 16-col tile
        bf16x8 f[4];
#pragma unroll
        for (int c0 = 0; c0 < 4; ++c0)
            f[c0] = *(const bf16x8*)&xt[(16 * c0 + (lane & 15)) * 136 + 32 * w + 8 * (lane >> 4)];
#pragma unroll
        for (int p = 0; p < 4; ++p)
#pragma unroll
            for (int q = 0; q < 4; ++q)
                acc[p][q] = __builtin_amdgcn_mfma_f32_16x16x32_bf16(f[p], f[q], acc[p][q], 0, 0, 0);
    }

    __syncthreads();                             // xt dead; reuse smem
    ((float4*)(smem + 4096))[t] = make_float4(s0, s1, s2, s3);
    int qd = lane >> 4, cl = lane & 15;
    if (w == 0) {
#pragma unroll
        for (int p = 0; p < 4; ++p)
#pragma unroll
            for (int q = 0; q < 4; ++q)
#pragma unroll
                for (int i = 0; i < 4; ++i)
                    smem[(16 * p + 4 * qd + i) * 64 + 16 * q + cl] = acc[p][q][i];
    }
    __syncthreads();
    if (t < 64) {                                // wave0: segment-sum reduce + atomic
        int cc4 = t >> 2, ii = t & 3;
        float s = 0;
#pragma unroll
        for (int u = 0; u < 16; ++u) s += smem[4096 + 4 * (cc4 + 16 * u) + ii];
        atomicAdd(&ssumg[seg * 64 + t], s);
    }
    for (int ww = 1; ww < 4; ++ww) {
        if (w == ww) {
#pragma unroll
            for (int p = 0; p < 4; ++p)
#pragma unroll
                for (int q = 0; q < 4; ++q)
#pragma unroll
                    for (int i = 0; i < 4; ++i)
                        smem[(16 * p + 4 * qd + i) * 64 + 16 * q + cl] += acc[p][q][i];
        }
        __syncthreads();
    }
    for (int f2 = t; f2 < 4096; f2 += 256) atomicAdd(&m2g[f2], smem[f2]);
}

// ---------------- K2b: tiny algebra -> wpb (bf16), tb ----------------
__global__ __launch_bounds__(256)
void k2b_solve(const int* __restrict__ o,
               const float* __restrict__ w2, const float* __restrict__ b2,
               const float* __restrict__ w1, const float* __restrict__ b1,
               const float* __restrict__ gamma, const float* __restrict__ beta,
               const float* __restrict__ m2, const float* __restrict__ ssum,
               unsigned short* __restrict__ wpb, float* __restrict__ tbout)
{
    __shared__ float means[512], hb[512], cv[512], Sx[64], cnts[8], muS[64], sS[64], q1p[256];
    int t = threadIdx.x;
    if (t < 8) cnts[t] = (float)(o[t] - (t ? o[t - 1] : 0));
    __syncthreads();
    for (int i = t; i < 512; i += 256) means[i] = ssum[i] / cnts[i >> 6];
    __syncthreads();
    int c = t & 63, g = t >> 6;
    for (int b = g; b < 8; b += 4) {
        float a = b2[c];
        for (int k = 0; k < 64; ++k) a = fmaf(means[b * 64 + k], w2[c * 64 + k], a);
        hb[b * 64 + c] = fmaxf(a, 0.f);
    }
    __syncthreads();
    for (int b = g; b < 8; b += 4) {
        float a = b1[c];
        for (int k = 0; k < 64; ++k) a = fmaf(hb[b * 64 + k], w1[c * 128 + 64 + k], a);
        cv[b * 64 + c] = a;
    }
    __syncthreads();
    if (t < 64) {
        float s = 0;
        for (int b = 0; b < 8; ++b) s += ssum[b * 64 + t];
        Sx[t] = s;
    }
    __syncthreads();
    {
        float p = 0;
        for (int j = g * 16; j < g * 16 + 16; ++j) {
            float vj = 0;
            for (int k = 0; k < 64; ++k) vj = fmaf(w1[c * 128 + k], m2[j * 64 + k], vj);
            p = fmaf(w1[c * 128 + j], vj, p);
        }
        q1p[g * 64 + c] = p;
    }
    __syncthreads();
    if (t < 64) {
        const float Nf = (float)NROWS;
        float mu = 0;
        for (int k = 0; k < 64; ++k) mu = fmaf(w1[t * 128 + k], Sx[k], mu);
        float q2 = 0, q3 = 0, msum = 0;
        for (int b = 0; b < 8; ++b) {
            float gv = cv[b * 64 + t];
            msum += cnts[b] * gv;
            q3 = fmaf(cnts[b] * gv, gv, q3);
            float dot = 0;
            for (int k = 0; k < 64; ++k) dot = fmaf(w1[t * 128 + k], ssum[b * 64 + k], dot);
            q2 = fmaf(2.f * gv, dot, q2);
        }
        mu = (mu + msum) / Nf;
        float q1 = q1p[t] + q1p[64 + t] + q1p[128 + t] + q1p[192 + t];
        float var = (q1 + q2 + q3) / Nf - mu * mu;
        float s = gamma[t] * rsqrtf(var + 1e-5f);
        muS[t] = mu; sS[t] = s;
    }
    __syncthreads();
    for (int f = t; f < 4096; f += 256)         // W'[c][k] bf16, row-major (B-frag ready)
        wpb[f] = f2bf(w1[(f >> 6) * 128 + (f & 63)] * sS[f >> 6]);
    for (int f = t; f < 512; f += 256)
        tbout[f] = (cv[f] - muS[f & 63]) * sS[f & 63] + beta[f & 63];
}

// ---------------- K3: out = relu(x @ W'^T + tb[seg]) via bf16 MFMA ----------------
__global__ __launch_bounds__(256, 3)
void k3_gemm(const float* __restrict__ x, const unsigned short* __restrict__ wpb,
             const float* __restrict__ tb, float* __restrict__ out)
{
    __shared__ __align__(16) short bt[64 * 72];  // W' tile, stride 72 shorts
    __shared__ float tbs[512];
    int t = threadIdx.x, lane = t & 63, w = t >> 6;
    size_t r0 = (size_t)blockIdx.x * 256;

    for (int f = t; f < 512; f += 256) {         // stage W' (8 KB) to LDS
        int c = f >> 3, kg = f & 7;
        uint4 vv = ((const uint4*)wpb)[f];
        *(uint4*)&bt[c * 72 + kg * 8] = vv;
    }
    for (int f = t; f < 512; f += 256) tbs[f] = tb[f];
    __syncthreads();

    int cl = lane & 15, qd = lane >> 4;
    bf16x8 B[4][2];
#pragma unroll
    for (int n = 0; n < 4; ++n)
#pragma unroll
        for (int k0 = 0; k0 < 2; ++k0)
            B[n][k0] = *(const bf16x8*)&bt[(16 * n + cl) * 72 + 32 * k0 + 8 * qd];

    int rbase = (int)r0 + 64 * w;
    f32x4 acc[4][4];
#pragma unroll
    for (int m = 0; m < 4; ++m)
#pragma unroll
        for (int n = 0; n < 4; ++n) acc[m][n] = (f32x4){0.f, 0.f, 0.f, 0.f};

#pragma unroll
    for (int m = 0; m < 4; ++m) {
        // A-frags straight from global: lane reads 32 B contiguous fp32 per frag
        const float* rp = x + (size_t)(rbase + 16 * m + cl) * 64 + 8 * qd;
        float4 u0 = *(const float4*)(rp);
        float4 u1 = *(const float4*)(rp + 4);
        float4 u2 = *(const float4*)(rp + 32);
        float4 u3 = *(const float4*)(rp + 36);
        bf16x8 A0, A1;
        A0[0] = (short)f2bf(u0.x); A0[1] = (short)f2bf(u0.y);
        A0[2] = (short)f2bf(u0.z); A0[3] = (short)f2bf(u0.w);
        A0[4] = (short)f2bf(u1.x); A0[5] = (short)f2bf(u1.y);
        A0[6] = (short)f2bf(u1.z); A0[7] = (short)f2bf(u1.w);
        A1[0] = (short)f2bf(u2.x); A1[1] = (short)f2bf(u2.y);
        A1[2] = (short)f2bf(u2.z); A1[3] = (short)f2bf(u2.w);
        A1[4] = (short)f2bf(u3.x); A1[5] = (short)f2bf(u3.y);
        A1[6] = (short)f2bf(u3.z); A1[7] = (short)f2bf(u3.w);
#pragma unroll
        for (int n = 0; n < 4; ++n) {
            acc[m][n] = __builtin_amdgcn_mfma_f32_16x16x32_bf16(A0, B[n][0], acc[m][n], 0, 0, 0);
            acc[m][n] = __builtin_amdgcn_mfma_f32_16x16x32_bf16(A1, B[n][1], acc[m][n], 0, 0, 0);
        }
    }

    // epilogue: +tb[seg], relu, direct stores (16 lanes = 64 B runs)
    int seg0 = rbase / SEGROWS;
    int bnd = (seg0 + 1) * SEGROWS;
    int seg1 = min(seg0 + 1, 7);
    float tA[4], tB[4];
#pragma unroll
    for (int n = 0; n < 4; ++n) {
        tA[n] = tbs[seg0 * 64 + 16 * n + cl];
        tB[n] = tbs[seg1 * 64 + 16 * n + cl];
    }
#pragma unroll
    for (int m = 0; m < 4; ++m)
#pragma unroll
        for (int i = 0; i < 4; ++i) {
            int grow = rbase + 16 * m + 4 * qd + i;
            bool hi = grow >= bnd;
#pragma unroll
            for (int n = 0; n < 4; ++n) {
                float tv = hi ? tB[n] : tA[n];
                float vv = fmaxf(acc[m][n][i] + tv, 0.f);
                out[(size_t)grow * 64 + 16 * n + cl] = vv;
            }
        }
}

extern "C" void kernel_launch(void* const* d_in, const int* in_sizes, int n_in,
                              void* d_out, int out_size, void* d_ws, size_t ws_size,
                              hipStream_t stream)
{
    const float* x  = (const float*)d_in[0];
    const int*   o  = (const int*)d_in[1];
    const float* w2 = (const float*)d_in[2];
    const float* b2 = (const float*)d_in[3];
    const float* w1 = (const float*)d_in[4];
    const float* b1 = (const float*)d_in[5];
    const float* gm = (const float*)d_in[6];
    const float* bt = (const float*)d_in[7];
    float* out = (float*)d_out;
    float* ws  = (float*)d_ws;

    float*          m2g  = ws;
    float*          ssum = ws + 4096;
    float*          tbv  = ws + 4608;
    unsigned short* wpb  = (unsigned short*)(ws + 5120);

    kzero<<<18, 256, 0, stream>>>(ws);
    k1_stats<<<K1_BLOCKS, 256, 0, stream>>>(x, m2g, ssum);
    k2b_solve<<<1, 256, 0, stream>>>(o, w2, b2, w1, b1, gm, bt, m2g, ssum, wpb, tbv);
    k3_gemm<<<3125, 256, 0, stream>>>(x, wpb, tbv, out);
}